// Round 8
// baseline (378.729 us; speedup 1.0000x reference)
//
#include <hip/hip_runtime.h>
#include <math.h>

#define CDIV(a,b) (((a)+(b)-1)/(b))

// ---------- deg[dst]++ (int histogram) ----------
__global__ __launch_bounds__(256) void deg_kernel(
    const int* __restrict__ dst, int E, int* __restrict__ deg)
{
    int e = blockIdx.x * 256 + threadIdx.x;
    if (e >= E) return;
    atomicAdd(&deg[dst[e]], 1);
}

__global__ __launch_bounds__(256) void dinv_kernel(
    const int* __restrict__ deg, float* __restrict__ dinv, int N)
{
    int i = blockIdx.x * 256 + threadIdx.x;
    if (i >= N) return;
    dinv[i] = 1.0f / sqrtf((float)deg[i] + 1.0f);  // +1 for self-loop
}

// ---------- hierarchical exclusive scan ----------
__global__ __launch_bounds__(1024) void block_scan_kernel(
    const int* __restrict__ deg, int* __restrict__ excl,
    int* __restrict__ bsums, int N)
{
    __shared__ int buf[1024];
    const int t = threadIdx.x;
    const int i = blockIdx.x * 1024 + t;
    int v = (i < N) ? deg[i] : 0;
    buf[t] = v;
    __syncthreads();
    for (int offs = 1; offs < 1024; offs <<= 1) {
        int add = (t >= offs) ? buf[t - offs] : 0;
        __syncthreads();
        buf[t] += add;
        __syncthreads();
    }
    if (i < N) excl[i] = buf[t] - v;
    if (t == 1023) bsums[blockIdx.x] = buf[t];
}

__global__ __launch_bounds__(1024) void scan_bsums_kernel(
    int* __restrict__ bsums, int nb)
{
    __shared__ int buf[1024];
    const int t = threadIdx.x;
    int v = (t < nb) ? bsums[t] : 0;
    buf[t] = v;
    __syncthreads();
    for (int offs = 1; offs < 1024; offs <<= 1) {
        int add = (t >= offs) ? buf[t - offs] : 0;
        __syncthreads();
        buf[t] += add;
        __syncthreads();
    }
    if (t < nb) bsums[t] = buf[t] - v;  // exclusive
}

__global__ __launch_bounds__(256) void add_offsets_kernel(
    int* __restrict__ rowptr, int* __restrict__ cursor,
    const int* __restrict__ bsums, int N, int E)
{
    int i = blockIdx.x * 256 + threadIdx.x;
    if (i < N) {
        int v = rowptr[i] + bsums[i >> 10];
        rowptr[i] = v;
        cursor[i] = v;
    }
    if (i == N) rowptr[N] = E;
}

// ---------- scatter edges into CSR slots ----------
__global__ __launch_bounds__(256) void csr_build_kernel(
    const int* __restrict__ src, const int* __restrict__ dst,
    int* __restrict__ cursor, int* __restrict__ csr_src, int E)
{
    int e = blockIdx.x * 256 + threadIdx.x;
    if (e >= E) return;
    int pos = atomicAdd(&cursor[dst[e]], 1);
    csr_src[pos] = src[e];
}

// ---------- GEMM: tmp = A@W ----------
// W (col-slice) staged in LDS once, single barrier, barrier-free k-loop.
// CHUNK16: store tmp in chunked layout [FO/16][N][16] for XCD-resident agg.
template<int FI, int FO, int COLS, int ROWS, bool CHUNK16>
__global__ __launch_bounds__(256, 4) void gemm_kernel(
    const float* __restrict__ A, const float* __restrict__ W,
    float* __restrict__ tmp, int N)
{
    constexpr int NCB = FO / COLS;    // col-blocks
    constexpr int CT  = COLS / 4;     // col-threads (float4 each)
    constexpr int RT  = 256 / CT;     // row-threads
    constexpr int RPT = ROWS / RT;    // rows per thread

    __shared__ float sW[FI][COLS];

    const int t    = threadIdx.x;
    const int colb = (NCB > 1) ? (blockIdx.x % NCB) : 0;
    const int rowb = (NCB > 1) ? (blockIdx.x / NCB) : blockIdx.x;

    #pragma unroll
    for (int it = 0; it < (FI * COLS / 4) / 256; ++it) {
        int idx = it * 256 + t;
        int k   = idx / CT;
        int cq  = idx % CT;
        *reinterpret_cast<float4*>(&sW[k][cq * 4]) =
            *reinterpret_cast<const float4*>(W + (size_t)k * FO + colb * COLS + cq * 4);
    }
    __syncthreads();

    const int c0 = (t % CT) * 4;
    const int r0 = t / CT;

    const float* aptr[RPT];
    #pragma unroll
    for (int rr = 0; rr < RPT; ++rr) {
        int row = rowb * ROWS + r0 + rr * RT;
        int rc  = (row < N) ? row : (N - 1);   // clamp loads, guard stores
        aptr[rr] = A + (size_t)rc * FI;
    }

    float acc[RPT][4];
    #pragma unroll
    for (int rr = 0; rr < RPT; ++rr)
        #pragma unroll
        for (int c = 0; c < 4; ++c) acc[rr][c] = 0.0f;

    #pragma unroll 8
    for (int k4 = 0; k4 < FI / 4; ++k4) {
        float4 w0 = *reinterpret_cast<const float4*>(&sW[k4 * 4 + 0][c0]);
        float4 w1 = *reinterpret_cast<const float4*>(&sW[k4 * 4 + 1][c0]);
        float4 w2 = *reinterpret_cast<const float4*>(&sW[k4 * 4 + 2][c0]);
        float4 w3 = *reinterpret_cast<const float4*>(&sW[k4 * 4 + 3][c0]);
        #pragma unroll
        for (int rr = 0; rr < RPT; ++rr) {
            float4 a = *reinterpret_cast<const float4*>(aptr[rr] + k4 * 4);
            acc[rr][0] += a.x * w0.x + a.y * w1.x + a.z * w2.x + a.w * w3.x;
            acc[rr][1] += a.x * w0.y + a.y * w1.y + a.z * w2.y + a.w * w3.y;
            acc[rr][2] += a.x * w0.z + a.y * w1.z + a.z * w2.z + a.w * w3.z;
            acc[rr][3] += a.x * w0.w + a.y * w1.w + a.z * w2.w + a.w * w3.w;
        }
    }

    const int gc0 = colb * COLS + c0;
    #pragma unroll
    for (int rr = 0; rr < RPT; ++rr) {
        int row = rowb * ROWS + r0 + rr * RT;
        if (row >= N) continue;
        float4 v = make_float4(acc[rr][0], acc[rr][1], acc[rr][2], acc[rr][3]);
        if (CHUNK16) {
            // chunk = gc0/16; float4 never crosses a 16-col boundary (gc0 % 4 == 0)
            *reinterpret_cast<float4*>(tmp + (size_t)(gc0 >> 4) * N * 16
                                           + (size_t)row * 16 + (gc0 & 15)) = v;
        } else {
            *reinterpret_cast<float4*>(tmp + (size_t)row * FO + gc0) = v;
        }
    }
}

// ---------- chunked gather aggregation (XCD-resident column chunk) ----------
// tmp layout [NC][N][16]; chunk = blockIdx.x % NC so each XCD (bid%8) sees one
// chunk (NC=8: 1/XCD; NC=4: chunk=xcd%4). One node per wave; 16 edge-slots of
// 4 lanes (float4 each); U=2 deep. Cross-slot shfl_xor reduce, then
// self-loop + bias + ReLU; writes its 16-col slice of h[node][FOFULL].
template<int FOFULL>
__global__ __launch_bounds__(256) void agg_chunk_kernel(
    const int* __restrict__ rowptr, const int* __restrict__ csr_src,
    const float* __restrict__ dinv, const float* __restrict__ tmp,
    const float* __restrict__ b, float* __restrict__ h, int N)
{
    constexpr int NC = FOFULL / 16;
    const int bid   = blockIdx.x;
    const int chunk = bid % NC;
    const int node  = (bid / NC) * 4 + (threadIdx.x >> 6);
    if (node >= N) return;
    const int lane = threadIdx.x & 63;
    const int g    = lane >> 2;   // edge slot 0..15
    const int f    = lane & 3;    // float4 index within 16-col chunk

    const float* tc = tmp + (size_t)chunk * N * 16;
    const float dvd = dinv[node];
    const int jb = rowptr[node], je = rowptr[node + 1];

    float4 a0 = make_float4(0.f, 0.f, 0.f, 0.f);
    float4 a1 = make_float4(0.f, 0.f, 0.f, 0.f);
    for (int j0 = jb; j0 < je; j0 += 32) {
        int j1 = j0 + g;
        if (j1 < je) {
            int s = csr_src[j1];
            float w = dinv[s] * dvd;
            float4 v = *reinterpret_cast<const float4*>(tc + (size_t)s * 16 + f * 4);
            a0.x += v.x * w; a0.y += v.y * w; a0.z += v.z * w; a0.w += v.w * w;
        }
        int j2 = j0 + 16 + g;
        if (j2 < je) {
            int s = csr_src[j2];
            float w = dinv[s] * dvd;
            float4 v = *reinterpret_cast<const float4*>(tc + (size_t)s * 16 + f * 4);
            a1.x += v.x * w; a1.y += v.y * w; a1.z += v.z * w; a1.w += v.w * w;
        }
    }
    float4 a = make_float4(a0.x + a1.x, a0.y + a1.y, a0.z + a1.z, a0.w + a1.w);
    #pragma unroll
    for (int m = 4; m < 64; m <<= 1) {
        a.x += __shfl_xor(a.x, m, 64);
        a.y += __shfl_xor(a.y, m, 64);
        a.z += __shfl_xor(a.z, m, 64);
        a.w += __shfl_xor(a.w, m, 64);
    }
    const float d2 = dvd * dvd;
    float4 sv = *reinterpret_cast<const float4*>(tc + (size_t)node * 16 + f * 4);
    const float4 bb = *reinterpret_cast<const float4*>(b + chunk * 16 + f * 4);
    a.x = fmaxf(a.x + sv.x * d2 + bb.x, 0.f);
    a.y = fmaxf(a.y + sv.y * d2 + bb.y, 0.f);
    a.z = fmaxf(a.z + sv.z * d2 + bb.z, 0.f);
    a.w = fmaxf(a.w + sv.w * d2 + bb.w, 0.f);
    if (g == 0)
        *reinterpret_cast<float4*>(h + (size_t)node * FOFULL + chunk * 16 + f * 4) = a;
}

// ---------- last-layer gather agg + fused final linear (unchunked, FO=32) ----------
template<int FO>
__global__ __launch_bounds__(256) void agg_final_kernel(
    const int* __restrict__ rowptr, const int* __restrict__ csr_src,
    const float* __restrict__ dinv, const float* __restrict__ tmp,
    const float* __restrict__ b,
    const float* __restrict__ Wl, const float* __restrict__ bl,
    float* __restrict__ out, int N)
{
    constexpr int GL = FO / 4;        // lanes per edge-slot (8)
    constexpr int EW = 64 / GL;       // edge-slots per wave (8)
    const int wid  = (blockIdx.x * 256 + threadIdx.x) >> 6;
    const int lane = threadIdx.x & 63;
    const int g    = lane / GL;
    const int f    = lane % GL;
    const int node = wid;
    if (node >= N) return;

    const float dvd = dinv[node];
    const int jb = rowptr[node], je = rowptr[node + 1];

    float4 a0 = make_float4(0.f, 0.f, 0.f, 0.f);
    float4 a1 = make_float4(0.f, 0.f, 0.f, 0.f);
    for (int j0 = jb; j0 < je; j0 += EW * 2) {
        int j1 = j0 + g;
        if (j1 < je) {
            int s = csr_src[j1];
            float w = dinv[s] * dvd;
            float4 v = *reinterpret_cast<const float4*>(tmp + (size_t)s * FO + f * 4);
            a0.x += v.x * w; a0.y += v.y * w; a0.z += v.z * w; a0.w += v.w * w;
        }
        int j2 = j0 + EW + g;
        if (j2 < je) {
            int s = csr_src[j2];
            float w = dinv[s] * dvd;
            float4 v = *reinterpret_cast<const float4*>(tmp + (size_t)s * FO + f * 4);
            a1.x += v.x * w; a1.y += v.y * w; a1.z += v.z * w; a1.w += v.w * w;
        }
    }
    float4 a = make_float4(a0.x + a1.x, a0.y + a1.y, a0.z + a1.z, a0.w + a1.w);
    #pragma unroll
    for (int m = GL; m < 64; m <<= 1) {
        a.x += __shfl_xor(a.x, m, 64);
        a.y += __shfl_xor(a.y, m, 64);
        a.z += __shfl_xor(a.z, m, 64);
        a.w += __shfl_xor(a.w, m, 64);
    }
    const float d2 = dvd * dvd;
    float4 sv = *reinterpret_cast<const float4*>(tmp + (size_t)node * FO + f * 4);
    const float4 bb = *reinterpret_cast<const float4*>(b + f * 4);
    a.x = fmaxf(a.x + sv.x * d2 + bb.x, 0.f);
    a.y = fmaxf(a.y + sv.y * d2 + bb.y, 0.f);
    a.z = fmaxf(a.z + sv.z * d2 + bb.z, 0.f);
    a.w = fmaxf(a.w + sv.w * d2 + bb.w, 0.f);

    const float4 wl = *reinterpret_cast<const float4*>(Wl + f * 4);
    float r = a.x * wl.x + a.y * wl.y + a.z * wl.z + a.w * wl.w;
    #pragma unroll
    for (int m = 1; m < GL; m <<= 1)
        r += __shfl_xor(r, m, 64);
    if (lane == 0) out[node] = r + bl[0];
}

extern "C" void kernel_launch(void* const* d_in, const int* in_sizes, int n_in,
                              void* d_out, int out_size, void* d_ws, size_t ws_size,
                              hipStream_t stream)
{
    const float* x  = (const float*)d_in[0];
    const int*   ei = (const int*)d_in[1];   // int inputs arrive as int32
    const float* W1 = (const float*)d_in[2];
    const float* b1 = (const float*)d_in[3];
    const float* W2 = (const float*)d_in[4];
    const float* b2 = (const float*)d_in[5];
    const float* W3 = (const float*)d_in[6];
    const float* b3 = (const float*)d_in[7];
    const float* Wl = (const float*)d_in[8];
    const float* bl = (const float*)d_in[9];
    float* out = (float*)d_out;

    const int N = in_sizes[0] / 128;
    const int E = in_sizes[1] / 2;

    const int* src = ei;        // edge_index row 0
    const int* dst = ei + E;    // edge_index row 1

    char* ws = (char*)d_ws;
    size_t off = 0;
    auto wsalloc = [&](size_t bytes) -> void* {
        void* p = ws + off;
        off = (off + bytes + 255) & ~(size_t)255;
        return p;
    };
    const int NB = CDIV(N, 1024);
    int*   deg     = (int*)  wsalloc((size_t)N * 4);
    float* dinv    = (float*)wsalloc((size_t)N * 4);
    int*   rowptr  = (int*)  wsalloc((size_t)(N + 1) * 4);
    int*   cursor  = (int*)  wsalloc((size_t)N * 4);
    int*   bsums   = (int*)  wsalloc((size_t)NB * 4);
    int*   csr_src = (int*)  wsalloc((size_t)E * 4);
    float* B1      = (float*)wsalloc((size_t)N * 128 * 4);  // tmp (chunked for L1/L2)
    float* B2      = (float*)wsalloc((size_t)N * 128 * 4);  // h
    // total ws use: ~55 MB

    // ---- CSR build ----
    hipMemsetAsync(deg, 0, (size_t)N * 4, stream);
    deg_kernel<<<CDIV(E, 256), 256, 0, stream>>>(dst, E, deg);
    dinv_kernel<<<CDIV(N, 256), 256, 0, stream>>>(deg, dinv, N);
    block_scan_kernel<<<NB, 1024, 0, stream>>>(deg, rowptr, bsums, N);
    scan_bsums_kernel<<<1, 1024, 0, stream>>>(bsums, NB);
    add_offsets_kernel<<<CDIV(N + 1, 256), 256, 0, stream>>>(rowptr, cursor, bsums, N, E);
    csr_build_kernel<<<CDIV(E, 256), 256, 0, stream>>>(src, dst, cursor, csr_src, E);

    // ---- layer 1: 128 -> 128 (chunked tmp, 8 chunks, 1 per XCD) ----
    gemm_kernel<128, 128, 64, 64, true><<<2 * CDIV(N, 64), 256, 0, stream>>>(x, W1, B1, N);
    agg_chunk_kernel<128><<<8 * CDIV(N, 4), 256, 0, stream>>>(
        rowptr, csr_src, dinv, B1, b1, B2, N);

    // ---- layer 2: 128 -> 64 (chunked tmp, 4 chunks, xcd%4) ----
    gemm_kernel<128, 64, 64, 64, true><<<CDIV(N, 64), 256, 0, stream>>>(B2, W2, B1, N);
    agg_chunk_kernel<64><<<4 * CDIV(N, 4), 256, 0, stream>>>(
        rowptr, csr_src, dinv, B1, b2, B2, N);

    // ---- layer 3: 64 -> 32, final linear fused (unchunked) ----
    gemm_kernel<64, 32, 32, 64, false><<<CDIV(N, 64), 256, 0, stream>>>(B2, W3, B1, N);
    agg_final_kernel<32><<<CDIV(N, 4), 256, 0, stream>>>(
        rowptr, csr_src, dinv, B1, b3, Wl, bl, out, N);
}

// Round 9
// 325.364 us; speedup vs baseline: 1.1640x; 1.1640x over previous
//
#include <hip/hip_runtime.h>
#include <math.h>

#define CDIV(a,b) (((a)+(b)-1)/(b))

// ---------- deg[dst]++ (int histogram) ----------
__global__ __launch_bounds__(256) void deg_kernel(
    const int* __restrict__ dst, int E, int* __restrict__ deg)
{
    int e = blockIdx.x * 256 + threadIdx.x;
    if (e >= E) return;
    atomicAdd(&deg[dst[e]], 1);
}

__global__ __launch_bounds__(256) void dinv_kernel(
    const int* __restrict__ deg, float* __restrict__ dinv, int N)
{
    int i = blockIdx.x * 256 + threadIdx.x;
    if (i >= N) return;
    dinv[i] = 1.0f / sqrtf((float)deg[i] + 1.0f);  // +1 for self-loop
}

// ---------- hierarchical exclusive scan ----------
__global__ __launch_bounds__(1024) void block_scan_kernel(
    const int* __restrict__ deg, int* __restrict__ excl,
    int* __restrict__ bsums, int N)
{
    __shared__ int buf[1024];
    const int t = threadIdx.x;
    const int i = blockIdx.x * 1024 + t;
    int v = (i < N) ? deg[i] : 0;
    buf[t] = v;
    __syncthreads();
    for (int offs = 1; offs < 1024; offs <<= 1) {
        int add = (t >= offs) ? buf[t - offs] : 0;
        __syncthreads();
        buf[t] += add;
        __syncthreads();
    }
    if (i < N) excl[i] = buf[t] - v;
    if (t == 1023) bsums[blockIdx.x] = buf[t];
}

__global__ __launch_bounds__(1024) void scan_bsums_kernel(
    int* __restrict__ bsums, int nb)
{
    __shared__ int buf[1024];
    const int t = threadIdx.x;
    int v = (t < nb) ? bsums[t] : 0;
    buf[t] = v;
    __syncthreads();
    for (int offs = 1; offs < 1024; offs <<= 1) {
        int add = (t >= offs) ? buf[t - offs] : 0;
        __syncthreads();
        buf[t] += add;
        __syncthreads();
    }
    if (t < nb) bsums[t] = buf[t] - v;  // exclusive
}

__global__ __launch_bounds__(256) void add_offsets_kernel(
    int* __restrict__ rowptr, int* __restrict__ cursor,
    const int* __restrict__ bsums, int N, int E)
{
    int i = blockIdx.x * 256 + threadIdx.x;
    if (i < N) {
        int v = rowptr[i] + bsums[i >> 10];
        rowptr[i] = v;
        cursor[i] = v;
    }
    if (i == N) rowptr[N] = E;
}

// ---------- scatter edges into CSR slots ----------
__global__ __launch_bounds__(256) void csr_build_kernel(
    const int* __restrict__ src, const int* __restrict__ dst,
    int* __restrict__ cursor, int* __restrict__ csr_src, int E)
{
    int e = blockIdx.x * 256 + threadIdx.x;
    if (e >= E) return;
    int pos = atomicAdd(&cursor[dst[e]], 1);
    csr_src[pos] = src[e];
}

// ---------- GEMM: tmp = A@W ----------
// W (col-slice) staged in LDS once, single barrier, barrier-free k-loop.
// CHUNK16: store tmp in chunked layout [FO/16][N][16] for XCD-resident agg.
template<int FI, int FO, int COLS, int ROWS, bool CHUNK16>
__global__ __launch_bounds__(256, 4) void gemm_kernel(
    const float* __restrict__ A, const float* __restrict__ W,
    float* __restrict__ tmp, int N)
{
    constexpr int NCB = FO / COLS;    // col-blocks
    constexpr int CT  = COLS / 4;     // col-threads (float4 each)
    constexpr int RT  = 256 / CT;     // row-threads
    constexpr int RPT = ROWS / RT;    // rows per thread

    __shared__ float sW[FI][COLS];

    const int t    = threadIdx.x;
    const int colb = (NCB > 1) ? (blockIdx.x % NCB) : 0;
    const int rowb = (NCB > 1) ? (blockIdx.x / NCB) : blockIdx.x;

    #pragma unroll
    for (int it = 0; it < (FI * COLS / 4) / 256; ++it) {
        int idx = it * 256 + t;
        int k   = idx / CT;
        int cq  = idx % CT;
        *reinterpret_cast<float4*>(&sW[k][cq * 4]) =
            *reinterpret_cast<const float4*>(W + (size_t)k * FO + colb * COLS + cq * 4);
    }
    __syncthreads();

    const int c0 = (t % CT) * 4;
    const int r0 = t / CT;

    const float* aptr[RPT];
    #pragma unroll
    for (int rr = 0; rr < RPT; ++rr) {
        int row = rowb * ROWS + r0 + rr * RT;
        int rc  = (row < N) ? row : (N - 1);   // clamp loads, guard stores
        aptr[rr] = A + (size_t)rc * FI;
    }

    float acc[RPT][4];
    #pragma unroll
    for (int rr = 0; rr < RPT; ++rr)
        #pragma unroll
        for (int c = 0; c < 4; ++c) acc[rr][c] = 0.0f;

    #pragma unroll 8
    for (int k4 = 0; k4 < FI / 4; ++k4) {
        float4 w0 = *reinterpret_cast<const float4*>(&sW[k4 * 4 + 0][c0]);
        float4 w1 = *reinterpret_cast<const float4*>(&sW[k4 * 4 + 1][c0]);
        float4 w2 = *reinterpret_cast<const float4*>(&sW[k4 * 4 + 2][c0]);
        float4 w3 = *reinterpret_cast<const float4*>(&sW[k4 * 4 + 3][c0]);
        #pragma unroll
        for (int rr = 0; rr < RPT; ++rr) {
            float4 a = *reinterpret_cast<const float4*>(aptr[rr] + k4 * 4);
            acc[rr][0] += a.x * w0.x + a.y * w1.x + a.z * w2.x + a.w * w3.x;
            acc[rr][1] += a.x * w0.y + a.y * w1.y + a.z * w2.y + a.w * w3.y;
            acc[rr][2] += a.x * w0.z + a.y * w1.z + a.z * w2.z + a.w * w3.z;
            acc[rr][3] += a.x * w0.w + a.y * w1.w + a.z * w2.w + a.w * w3.w;
        }
    }

    const int gc0 = colb * COLS + c0;
    #pragma unroll
    for (int rr = 0; rr < RPT; ++rr) {
        int row = rowb * ROWS + r0 + rr * RT;
        if (row >= N) continue;
        float4 v = make_float4(acc[rr][0], acc[rr][1], acc[rr][2], acc[rr][3]);
        if (CHUNK16) {
            *reinterpret_cast<float4*>(tmp + (size_t)(gc0 >> 4) * N * 16
                                           + (size_t)row * 16 + (gc0 & 15)) = v;
        } else {
            *reinterpret_cast<float4*>(tmp + (size_t)row * FO + gc0) = v;
        }
    }
}

// ---------- chunked gather agg, node-slot parallel (no reduce tail) ----------
// tmp layout [NC][N][16]; chunk = bid % NC rides the XCD round-robin so each
// XCD touches one 3.2MB chunk. Wave = 16 node-slots x 4 lanes (float4 of the
// chunk). Each slot walks its own node's edge list serially (2 accumulators);
// accumulator lives in the slot's lanes -> tail is selfloop+bias+relu+store,
// amortized over 16 nodes/wave.
template<int FOFULL, int NC>
__global__ __launch_bounds__(256) void agg_chunk_kernel(
    const int* __restrict__ rowptr, const int* __restrict__ csr_src,
    const float* __restrict__ dinv, const float* __restrict__ tmp,
    const float* __restrict__ b, float* __restrict__ h, int N)
{
    const int bid   = blockIdx.x;
    const int chunk = bid % NC;
    const int lane  = threadIdx.x & 63;
    const int slot  = lane >> 2;     // 0..15
    const int f     = lane & 3;      // float4 index within 16-col chunk
    const int node  = (bid / NC) * 64 + (threadIdx.x >> 6) * 16 + slot;
    if (node >= N) return;

    const float* tc = tmp + (size_t)chunk * N * 16;
    const float dvd = dinv[node];
    const int jb = rowptr[node], je = rowptr[node + 1];

    float4 a0 = make_float4(0.f, 0.f, 0.f, 0.f);
    float4 a1 = make_float4(0.f, 0.f, 0.f, 0.f);
    for (int j = jb; j < je; j += 2) {
        int s0 = csr_src[j];
        float w0 = dinv[s0] * dvd;
        float4 v0 = *reinterpret_cast<const float4*>(tc + (size_t)s0 * 16 + f * 4);
        a0.x += v0.x * w0; a0.y += v0.y * w0; a0.z += v0.z * w0; a0.w += v0.w * w0;
        if (j + 1 < je) {
            int s1 = csr_src[j + 1];
            float w1 = dinv[s1] * dvd;
            float4 v1 = *reinterpret_cast<const float4*>(tc + (size_t)s1 * 16 + f * 4);
            a1.x += v1.x * w1; a1.y += v1.y * w1; a1.z += v1.z * w1; a1.w += v1.w * w1;
        }
    }
    const float d2 = dvd * dvd;
    float4 sv = *reinterpret_cast<const float4*>(tc + (size_t)node * 16 + f * 4);
    const float4 bb = *reinterpret_cast<const float4*>(b + chunk * 16 + f * 4);
    float4 a;
    a.x = fmaxf(a0.x + a1.x + sv.x * d2 + bb.x, 0.f);
    a.y = fmaxf(a0.y + a1.y + sv.y * d2 + bb.y, 0.f);
    a.z = fmaxf(a0.z + a1.z + sv.z * d2 + bb.z, 0.f);
    a.w = fmaxf(a0.w + a1.w + sv.w * d2 + bb.w, 0.f);
    *reinterpret_cast<float4*>(h + (size_t)node * FOFULL + chunk * 16 + f * 4) = a;
}

// ---------- last layer: node-slot agg + fused final linear (FO=32) ----------
// Wave = 8 node-slots x 8 lanes (float4 each). Dot with Wl per lane, 3-round
// shuffle reduce within the 8-lane slot, lane f==0 writes out[node].
__global__ __launch_bounds__(256) void agg_final_kernel(
    const int* __restrict__ rowptr, const int* __restrict__ csr_src,
    const float* __restrict__ dinv, const float* __restrict__ tmp,
    const float* __restrict__ b,
    const float* __restrict__ Wl, const float* __restrict__ bl,
    float* __restrict__ out, int N)
{
    constexpr int FO = 32;
    const int lane = threadIdx.x & 63;
    const int slot = lane >> 3;      // 0..7
    const int f    = lane & 7;       // float4 index within 32-col row
    const int node = blockIdx.x * 32 + (threadIdx.x >> 6) * 8 + slot;
    if (node >= N) return;

    const float dvd = dinv[node];
    const int jb = rowptr[node], je = rowptr[node + 1];

    float4 a0 = make_float4(0.f, 0.f, 0.f, 0.f);
    float4 a1 = make_float4(0.f, 0.f, 0.f, 0.f);
    for (int j = jb; j < je; j += 2) {
        int s0 = csr_src[j];
        float w0 = dinv[s0] * dvd;
        float4 v0 = *reinterpret_cast<const float4*>(tmp + (size_t)s0 * FO + f * 4);
        a0.x += v0.x * w0; a0.y += v0.y * w0; a0.z += v0.z * w0; a0.w += v0.w * w0;
        if (j + 1 < je) {
            int s1 = csr_src[j + 1];
            float w1 = dinv[s1] * dvd;
            float4 v1 = *reinterpret_cast<const float4*>(tmp + (size_t)s1 * FO + f * 4);
            a1.x += v1.x * w1; a1.y += v1.y * w1; a1.z += v1.z * w1; a1.w += v1.w * w1;
        }
    }
    const float d2 = dvd * dvd;
    float4 sv = *reinterpret_cast<const float4*>(tmp + (size_t)node * FO + f * 4);
    const float4 bb = *reinterpret_cast<const float4*>(b + f * 4);
    float4 a;
    a.x = fmaxf(a0.x + a1.x + sv.x * d2 + bb.x, 0.f);
    a.y = fmaxf(a0.y + a1.y + sv.y * d2 + bb.y, 0.f);
    a.z = fmaxf(a0.z + a1.z + sv.z * d2 + bb.z, 0.f);
    a.w = fmaxf(a0.w + a1.w + sv.w * d2 + bb.w, 0.f);

    const float4 wl = *reinterpret_cast<const float4*>(Wl + f * 4);
    float r = a.x * wl.x + a.y * wl.y + a.z * wl.z + a.w * wl.w;
    r += __shfl_xor(r, 1, 64);
    r += __shfl_xor(r, 2, 64);
    r += __shfl_xor(r, 4, 64);
    if (f == 0) out[node] = r + bl[0];
}

extern "C" void kernel_launch(void* const* d_in, const int* in_sizes, int n_in,
                              void* d_out, int out_size, void* d_ws, size_t ws_size,
                              hipStream_t stream)
{
    const float* x  = (const float*)d_in[0];
    const int*   ei = (const int*)d_in[1];   // int inputs arrive as int32
    const float* W1 = (const float*)d_in[2];
    const float* b1 = (const float*)d_in[3];
    const float* W2 = (const float*)d_in[4];
    const float* b2 = (const float*)d_in[5];
    const float* W3 = (const float*)d_in[6];
    const float* b3 = (const float*)d_in[7];
    const float* Wl = (const float*)d_in[8];
    const float* bl = (const float*)d_in[9];
    float* out = (float*)d_out;

    const int N = in_sizes[0] / 128;
    const int E = in_sizes[1] / 2;

    const int* src = ei;        // edge_index row 0
    const int* dst = ei + E;    // edge_index row 1

    char* ws = (char*)d_ws;
    size_t off = 0;
    auto wsalloc = [&](size_t bytes) -> void* {
        void* p = ws + off;
        off = (off + bytes + 255) & ~(size_t)255;
        return p;
    };
    const int NB = CDIV(N, 1024);
    int*   deg     = (int*)  wsalloc((size_t)N * 4);
    float* dinv    = (float*)wsalloc((size_t)N * 4);
    int*   rowptr  = (int*)  wsalloc((size_t)(N + 1) * 4);
    int*   cursor  = (int*)  wsalloc((size_t)N * 4);
    int*   bsums   = (int*)  wsalloc((size_t)NB * 4);
    int*   csr_src = (int*)  wsalloc((size_t)E * 4);
    float* B1      = (float*)wsalloc((size_t)N * 128 * 4);  // tmp (chunked)
    float* B2      = (float*)wsalloc((size_t)N * 128 * 4);  // h
    // total ws use: ~55 MB

    // ---- CSR build ----
    hipMemsetAsync(deg, 0, (size_t)N * 4, stream);
    deg_kernel<<<CDIV(E, 256), 256, 0, stream>>>(dst, E, deg);
    dinv_kernel<<<CDIV(N, 256), 256, 0, stream>>>(deg, dinv, N);
    block_scan_kernel<<<NB, 1024, 0, stream>>>(deg, rowptr, bsums, N);
    scan_bsums_kernel<<<1, 1024, 0, stream>>>(bsums, NB);
    add_offsets_kernel<<<CDIV(N + 1, 256), 256, 0, stream>>>(rowptr, cursor, bsums, N, E);
    csr_build_kernel<<<CDIV(E, 256), 256, 0, stream>>>(src, dst, cursor, csr_src, E);

    // ---- layer 1: 128 -> 128 (chunked tmp, NC=8, 1 chunk per XCD) ----
    gemm_kernel<128, 128, 64, 64, true><<<2 * CDIV(N, 64), 256, 0, stream>>>(x, W1, B1, N);
    agg_chunk_kernel<128, 8><<<8 * CDIV(N, 64), 256, 0, stream>>>(
        rowptr, csr_src, dinv, B1, b1, B2, N);

    // ---- layer 2: 128 -> 64 (chunked tmp, NC=4) ----
    gemm_kernel<128, 64, 64, 64, true><<<CDIV(N, 64), 256, 0, stream>>>(B2, W2, B1, N);
    agg_chunk_kernel<64, 4><<<4 * CDIV(N, 64), 256, 0, stream>>>(
        rowptr, csr_src, dinv, B1, b2, B2, N);

    // ---- layer 3: 64 -> 32, final linear fused (unchunked) ----
    gemm_kernel<64, 32, 32, 64, false><<<CDIV(N, 64), 256, 0, stream>>>(B2, W3, B1, N);
    agg_final_kernel<<<CDIV(N, 32), 256, 0, stream>>>(
        rowptr, csr_src, dinv, B1, b3, Wl, bl, out, N);
}